// Round 8
// baseline (703.354 us; speedup 1.0000x reference)
//
#include <hip/hip_runtime.h>
#include <cstdint>
#include <cstddef>

// RobustGCN forward on MI355X.
//   1. graph prep — bucket sort (bucket = src>>7), pairs PACKED to u32
//      ((src&127)<<25 | dst, valid for N < 2^25): halves pairs traffic.
//      hist -> btotal/bscan/boff -> bscatter(u32) -> countN(+dd) -> scans -> partC.
//      (r6: global-atomic scatter = 15x write-amp, 280us. Bucket-dense wins.)
//   2. GEMM1 v7 (gemm1s): BM=64 x BN=128, BK=32, 4 waves (2m x 2n), acc[2][4]
//      = 32 AGPR -> unified regs ~112/wave -> 4 waves/SIMD (vs 3 for the 128x128
//      acc[4][4]=64AGPR variant). LDS 32KB dbuf -> 4 blocks/CU. Same proven
//      pieces as r2/r7: A f32 + B f16 global_load_lds w16, linear dest +
//      inverse-swizzled src (A ^row&7 slots, B ^(row>>1)&3), cvt at frag build.
//      (r3: deep pipeline lost occupancy. r5: reg-staged A +49us: ds_write
//      traffic + cvt VALU, no occupancy gain — NOT just vmcnt stall.)
//   3. GEMM2 v2: gload16-staged (gemm1h layout, 0 bank conflicts), acc[2][8]
//      wave owns 32 rows x all 128 cols (mean+var in-register for the fused
//      attention epilogue) -> Mcat[r][c] = pack_h2(dis_r*m*e^-v, di_r*v*e^-2v).
//   4. fused dual SpMM (CSR, wave/node, lane/class, 8 gathers in flight) —
//      no dd gather (folded into Mcat) + sample*sqrt(var) + log_softmax.

typedef _Float16 h8 __attribute__((ext_vector_type(8)));
typedef _Float16 h2 __attribute__((ext_vector_type(2)));
typedef float f32x4 __attribute__((ext_vector_type(4)));
typedef unsigned int uint32;

#define BSHIFT 7              // 128 nodes per bucket
#define NCHUNK 256            // edge chunks (blocks) in sort passes

static __device__ __forceinline__ float elu_f(float z) {
  return z > 0.f ? z : expm1f(z);
}

// async global->LDS, 16B per lane. Dest must be wave-linear (base + lane*16).
static __device__ __forceinline__ void gload16(const void* g, void* l) {
  __builtin_amdgcn_global_load_lds(
      (__attribute__((address_space(1))) void*)g,
      (__attribute__((address_space(3))) void*)l, 16, 0, 0);
}

static __device__ __forceinline__ h8 cvt8(float4 a, float4 b) {
  return h8{(_Float16)a.x, (_Float16)a.y, (_Float16)a.z, (_Float16)a.w,
            (_Float16)b.x, (_Float16)b.y, (_Float16)b.z, (_Float16)b.w};
}

// ---------------- bucket sort ----------------
__global__ __launch_bounds__(256) void hist_k(const int* __restrict__ esrc, int E,
                                              int chunk, int* __restrict__ h, int NB) {
  __shared__ int sh[1024];
  int t = threadIdx.x;
  for (int i = t; i < NB; i += 256) sh[i] = 0;
  __syncthreads();
  int e0 = blockIdx.x * chunk;
  int e1 = min(e0 + chunk, E);
  for (int e = e0 + t; e < e1; e += 256) atomicAdd(&sh[esrc[e] >> BSHIFT], 1);
  __syncthreads();
  for (int i = t; i < NB; i += 256) h[blockIdx.x * NB + i] = sh[i];
}

__global__ __launch_bounds__(256) void btotal_k(const int* __restrict__ h,
                                                int* __restrict__ tot, int NB) {
  int b = blockIdx.x, t = threadIdx.x;
  int v = h[t * NB + b];
#pragma unroll
  for (int off = 32; off; off >>= 1) v += __shfl_xor(v, off, 64);
  __shared__ int sw[4];
  if ((t & 63) == 0) sw[t >> 6] = v;
  __syncthreads();
  if (t == 0) tot[b] = sw[0] + sw[1] + sw[2] + sw[3];
}

__global__ __launch_bounds__(1024) void bscan_k(const int* __restrict__ tot,
                                                int* __restrict__ base, int NB) {
  __shared__ int sh[1024];
  int t = threadIdx.x;
  int v = (t < NB) ? tot[t] : 0;
  sh[t] = v;
  __syncthreads();
  for (int off = 1; off < 1024; off <<= 1) {
    int add = (t >= off) ? sh[t - off] : 0;
    __syncthreads();
    sh[t] += add;
    __syncthreads();
  }
  if (t < NB) base[t] = sh[t] - v;
  if (t == 1023) base[NB] = sh[1023];
}

__global__ __launch_bounds__(256) void boff_k(int* __restrict__ h,
                                              const int* __restrict__ base, int NB) {
  __shared__ int sh[256];
  int b = blockIdx.x, t = threadIdx.x;
  int v = h[t * NB + b];
  sh[t] = v;
  __syncthreads();
  for (int off = 1; off < 256; off <<= 1) {
    int add = (t >= off) ? sh[t - off] : 0;
    __syncthreads();
    sh[t] += add;
    __syncthreads();
  }
  h[t * NB + b] = base[b] + sh[t] - v;
}

// packed pairs: (src&127)<<25 | dst   (dst < 2^25)
__global__ __launch_bounds__(256) void bscatter_k(
    const int* __restrict__ esrc, const int* __restrict__ edst, int E, int chunk,
    const int* __restrict__ h, uint32* __restrict__ pairs, int NB) {
  __shared__ int lcur[1024];
  int t = threadIdx.x;
  for (int i = t; i < NB; i += 256) lcur[i] = h[blockIdx.x * NB + i];
  __syncthreads();
  int e0 = blockIdx.x * chunk;
  int e1 = min(e0 + chunk, E);
  for (int e = e0 + t; e < e1; e += 256) {
    int s = esrc[e], d = edst[e];
    int pos = atomicAdd(&lcur[s >> BSHIFT], 1);
    pairs[pos] = ((uint32)(s & 127) << 25) | (uint32)d;
  }
}

// per-node degree (bucket sort makes per-bucket counts complete) + degree weights
__global__ __launch_bounds__(256) void countN_k(
    const uint32* __restrict__ pairs, const int* __restrict__ base,
    int* __restrict__ cnt, float2* __restrict__ dd, int n) {
  __shared__ int c128[128];
  int b = blockIdx.x, t = threadIdx.x;
  if (t < 128) c128[t] = 0;
  __syncthreads();
  int lo = base[b], hi = base[b + 1];
  for (int i = lo + t; i < hi; i += 256) atomicAdd(&c128[pairs[i] >> 25], 1);
  __syncthreads();
  if (t < 128) {
    int node = b * 128 + t;
    if (node < n) {
      int c = c128[t];
      cnt[node] = c;
      float d = (float)(c + 1);  // +1 self loop
      dd[node] = make_float2(rsqrtf(d), 1.f / d);
    }
  }
}

__global__ __launch_bounds__(256) void partC_k(
    const uint32* __restrict__ pairs, const int* __restrict__ base,
    const int* __restrict__ rs, int* __restrict__ csr, int n) {
  __shared__ int lcur[128];
  int b = blockIdx.x, t = threadIdx.x;
  if (t < 128) {
    int node = b * 128 + t;
    lcur[t] = (node < n) ? rs[node] : 0;
  }
  __syncthreads();
  int lo = base[b], hi = base[b + 1];
  for (int i = lo + t; i < hi; i += 256) {
    uint32 p = pairs[i];
    int pos = atomicAdd(&lcur[p >> 25], 1);
    csr[pos] = (int)(p & 0x1FFFFFFu);
  }
}

// ---------------- padded row-start scan ----------------
// exclusive scan of PADDED counts ((cnt+3)&~3) so every CSR row start is 16B-aligned
__global__ void scan1_k(const int* __restrict__ cnt, int* __restrict__ excl,
                        int* __restrict__ bsum, int n) {
  __shared__ int sh[256];
  int t = threadIdx.x, idx = blockIdx.x * 256 + t;
  int v = (idx < n) ? ((cnt[idx] + 3) & ~3) : 0;
  sh[t] = v;
  __syncthreads();
  for (int off = 1; off < 256; off <<= 1) {
    int add = (t >= off) ? sh[t - off] : 0;
    __syncthreads();
    sh[t] += add;
    __syncthreads();
  }
  if (idx < n) excl[idx] = sh[t] - v;
  if (t == 255) bsum[blockIdx.x] = sh[255];
}

__global__ void scan2_k(const int* __restrict__ bsum, int* __restrict__ boff, int nb) {
  __shared__ int sh[512];
  int t = threadIdx.x;
  int v = (t < nb) ? bsum[t] : 0;
  sh[t] = v;
  __syncthreads();
  for (int off = 1; off < 512; off <<= 1) {
    int add = (t >= off) ? sh[t - off] : 0;
    __syncthreads();
    sh[t] += add;
    __syncthreads();
  }
  if (t < nb) boff[t] = sh[t] - v;
}

__global__ void scan3_k(int* __restrict__ excl, const int* __restrict__ boff, int n) {
  int idx = blockIdx.x * 256 + threadIdx.x;
  if (idx < n) excl[idx] += boff[blockIdx.x];
}

// ---------------- weight prep: transpose + f16 + fuse ----------------
__global__ void prep_w_k(const float* __restrict__ Wm0, const float* __restrict__ Wv0,
                         const float* __restrict__ Wm1, const float* __restrict__ Wv1,
                         _Float16* __restrict__ W1t, _Float16* __restrict__ W2t) {
  int idx = blockIdx.x * 256 + threadIdx.x;
  if (idx < 512 * 512) {
    int n = idx >> 9, k = idx & 511;
    float v = (n < 256) ? Wm0[k * 256 + n] : Wv0[k * 256 + (n - 256)];
    W1t[idx] = (_Float16)v;
  }
  if (idx < 128 * 512) {
    int n = idx >> 9, k = idx & 511;
    float v = 0.f;
    if (n < 64) { if (k < 256) v = Wm1[k * 64 + n]; }
    else        { if (k >= 256) v = Wv1[(k - 256) * 64 + (n - 64)]; }
    W2t[idx] = (_Float16)v;
  }
}

// ---------------- GEMM1 v7 (gemm1s): Hcat = act(x @ W1t^T + b) ----------------
// BM=64, BN=128, BK=32, K=512. 4 waves (2m x 2n), wave = 32x64 out, acc[2][4].
// LDS 32KB: buf b: Af32[64][32] @ b*16384 (slot ^row&7),
//                  Bf16[128][32] @ b*16384+8192 (slot ^(row>>1)&3).
// 32 AGPR acc -> ~112 unified regs/wave -> 4 waves/SIMD; 4 blocks/CU.
__global__ __launch_bounds__(256) void gemm1s_k(
    const float* __restrict__ A, const _Float16* __restrict__ Bt,
    const float* __restrict__ b0, const float* __restrict__ b1,
    _Float16* __restrict__ out, int M, int mtiles) {
  __shared__ __align__(16) unsigned char ldsb[32768];

  const int sg = blockIdx.x >> 5, loc = blockIdx.x & 31;
  const int nt = loc >> 3, mtl = loc & 7;
  const int mt = sg * 8 + mtl;
  if (mt >= mtiles) return;
  const int m0 = mt * 64, n0 = nt * 128;
  const int t = threadIdx.x;
  const int lane = t & 63;
  const int wave = t >> 6;
  const int wm = wave >> 1, wn = wave & 1;
  const int lr = lane & 15, quad = lane >> 4;

  const int ra = t >> 3;                              // A row base (i*32 + ra)
  const int asw = ((t & 7) ^ (ra & 7)) << 2;          // inv-swizzled f32 col
  const int rb = t >> 2;                              // B row base (i*64 + rb)
  const int bsw = ((t & 3) ^ ((t >> 3) & 3)) << 3;    // inv-swizzled f16 col

  f32x4 acc[2][4] = {};

  auto stage = [&](int b, int kt) {
#pragma unroll
    for (int i = 0; i < 2; i++) {                     // A: 64 rows x 32 f32
      const float* src = A + (size_t)min(m0 + i * 32 + ra, M - 1) * 512 + kt + asw;
      gload16(src, ldsb + b * 16384 + i * 4096 + t * 16);
    }
#pragma unroll
    for (int i = 0; i < 2; i++) {                     // B: 128 rows x 32 f16
      const _Float16* src = Bt + (size_t)(n0 + i * 64 + rb) * 512 + kt + bsw;
      gload16(src, ldsb + b * 16384 + 8192 + i * 4096 + t * 16);
    }
  };

  stage(0, 0);
  __syncthreads();

  int cur = 0;
  const int zA = lr & 7;
  const int zB = (lr >> 1) & 3;
  for (int kt = 0; kt < 512; kt += 32) {
    if (kt + 32 < 512) stage(cur ^ 1, kt + 32);
    const unsigned char* Ab = ldsb + cur * 16384;
    const unsigned char* Bb = Ab + 8192;
    h8 bf[4];
#pragma unroll
    for (int j = 0; j < 4; j++) {
      int row = wn * 64 + j * 16 + lr;
      bf[j] = *(const h8*)(Bb + row * 64 + ((quad ^ zB) << 4));
    }
    h8 af[2];
#pragma unroll
    for (int i = 0; i < 2; i++) {
      int R = wm * 32 + i * 16 + lr;
      const float4 a0 = *(const float4*)(Ab + R * 128 + (((2 * quad) ^ zA) << 4));
      const float4 a1 = *(const float4*)(Ab + R * 128 + (((2 * quad + 1) ^ zA) << 4));
      af[i] = cvt8(a0, a1);
    }
#pragma unroll
    for (int i = 0; i < 2; i++)
#pragma unroll
      for (int j = 0; j < 4; j++)
        acc[i][j] = __builtin_amdgcn_mfma_f32_16x16x32_f16(af[i], bf[j], acc[i][j], 0, 0, 0);
    __syncthreads();
    cur ^= 1;
  }

  // epilogue: bias+act -> f16 LDS [64][136] (17KB) -> 16B coalesced stores
  _Float16* lt = (_Float16*)ldsb;
#pragma unroll
  for (int j = 0; j < 4; j++) {
    int gc = n0 + wn * 64 + j * 16 + lr;
    float bj = (gc < 256) ? b0[gc] : b1[gc - 256];
#pragma unroll
    for (int i = 0; i < 2; i++) {
#pragma unroll
      for (int r = 0; r < 4; r++) {
        float z = acc[i][j][r] + bj;
        float v = (gc < 256) ? elu_f(z) : fmaxf(z, 0.f);
        lt[(wm * 32 + i * 16 + quad * 4 + r) * 136 + wn * 64 + j * 16 + lr] = (_Float16)v;
      }
    }
  }
  __syncthreads();
  {
    const int row = t >> 2, c0 = (t & 3) * 32;
    const int gr = m0 + row;
    if (gr < M) {
      _Float16* dst = out + (size_t)gr * 512 + n0 + c0;
      const _Float16* srow = lt + row * 136 + c0;
#pragma unroll
      for (int k = 0; k < 4; k++)
        *(h8*)(dst + k * 8) = *(const h8*)(srow + k * 8);
    }
  }
}

// ---------------- GEMM2 v2 + fused attention (gload16-staged) ----------------
// BM=128, N=128 (cols 0..63 mean, 64..127 var). 4 waves, wave = 32 rows x 8 j-tiles
// (keeps mean+var for each row in-register for the pack). LDS 32KB dbuf,
// gemm1h's verified 0-conflict layout: both tiles 64B rows, slot ^(row>>1)&3.
// Epilogue folds dst-side degree weights: Mcat[r][c]=pack_h2(dis_r*m*a, di_r*v*a^2).
__global__ __launch_bounds__(256) void gemm2_k(
    const _Float16* __restrict__ A, const _Float16* __restrict__ Bt,
    const float* __restrict__ bm1, const float* __restrict__ bv1,
    const float2* __restrict__ dd, uint32* __restrict__ Mcat, int M) {
  __shared__ __align__(16) unsigned char ldsb[32768];
  const int m0 = blockIdx.x * 128;
  const int t = threadIdx.x;
  const int lane = t & 63;
  const int wave = t >> 6;
  const int lr = lane & 15, quad = lane >> 4;

  const int rb = t >> 2;
  const int sw = ((t & 3) ^ ((t >> 3) & 3)) << 3;     // inv-swizzled f16 col

  f32x4 acc[2][8] = {};

  auto stage = [&](int b, int kt) {
#pragma unroll
    for (int i = 0; i < 2; i++) {                     // A: 128 rows x 32 f16
      const _Float16* src = A + (size_t)min(m0 + i * 64 + rb, M - 1) * 512 + kt + sw;
      gload16(src, ldsb + b * 16384 + i * 4096 + t * 16);
    }
#pragma unroll
    for (int i = 0; i < 2; i++) {                     // B: 128 rows x 32 f16
      const _Float16* src = Bt + (size_t)(i * 64 + rb) * 512 + kt + sw;
      gload16(src, ldsb + b * 16384 + 8192 + i * 4096 + t * 16);
    }
  };

  stage(0, 0);
  __syncthreads();

  const int z = (lr >> 1) & 3;
  int cur = 0;
  for (int kt = 0; kt < 512; kt += 32) {
    if (kt + 32 < 512) stage(cur ^ 1, kt + 32);
    const unsigned char* Ab = ldsb + cur * 16384;
    const unsigned char* Bb = Ab + 8192;
    h8 af[2], bf[8];
#pragma unroll
    for (int i = 0; i < 2; i++) {
      int row = wave * 32 + i * 16 + lr;
      af[i] = *(const h8*)(Ab + row * 64 + ((quad ^ z) << 4));
    }
#pragma unroll
    for (int j = 0; j < 8; j++) {
      int row = j * 16 + lr;
      bf[j] = *(const h8*)(Bb + row * 64 + ((quad ^ z) << 4));
    }
#pragma unroll
    for (int i = 0; i < 2; i++)
#pragma unroll
      for (int j = 0; j < 8; j++)
        acc[i][j] = __builtin_amdgcn_mfma_f32_16x16x32_f16(af[i], bf[j], acc[i][j], 0, 0, 0);
    __syncthreads();
    cur ^= 1;
  }

  // per-thread row weights (8 rows), loaded once
  float2 wrow[2][4];
#pragma unroll
  for (int i = 0; i < 2; i++)
#pragma unroll
    for (int r = 0; r < 4; r++) {
      int gr = m0 + wave * 32 + i * 16 + quad * 4 + r;
      wrow[i][r] = (gr < M) ? dd[gr] : make_float2(0.f, 0.f);
    }

#pragma unroll
  for (int jm = 0; jm < 4; jm++) {
    int c = jm * 16 + lr;                 // class col 0..63
    float bm = bm1[c], bv = bv1[c];
#pragma unroll
    for (int i = 0; i < 2; i++) {
#pragma unroll
      for (int r = 0; r < 4; r++) {
        int gr = m0 + wave * 32 + i * 16 + quad * 4 + r;
        if (gr < M) {
          float zm = acc[i][jm][r] + bm;
          float zv = acc[i][4 + jm][r] + bv;
          float m = elu_f(zm);
          float v = fmaxf(zv, 0.f) + 1e-6f;
          float a = __expf(-v);
          h2 pk;
          pk.x = (_Float16)(m * a * wrow[i][r].x);       // dis_r * mean*attn
          pk.y = (_Float16)(v * a * a * wrow[i][r].y);   // di_r * var*attn^2
          Mcat[(size_t)gr * 64 + c] = __builtin_bit_cast(uint32, pk);
        }
      }
    }
  }
}

// ---------------- fused dual SpMM + reparam + log_softmax ----------------
// Mcat rows pre-scaled by dst weights -> pure gather+sum. 8 gathers in flight.
__global__ __launch_bounds__(256) void spmm_final_k(
    const uint32* __restrict__ Mcat, const float2* __restrict__ dd,
    const int* __restrict__ row_start, const int* __restrict__ cnt,
    const int* __restrict__ csr, const float* __restrict__ sample,
    float* __restrict__ out, int n) {
  int wid = threadIdx.x >> 6, lane = threadIdx.x & 63;
  int r = blockIdx.x * 4 + wid;
  if (r >= n) return;
  float2 wr = dd[r];
  h2 self = __builtin_bit_cast(h2, Mcat[(size_t)r * 64 + lane]);
  float Sm = (float)self.x;           // already dis_r-scaled
  float Sv = (float)self.y;           // already di_r-scaled
  int start = __builtin_amdgcn_readfirstlane(row_start[r]);
  int c = __builtin_amdgcn_readfirstlane(cnt[r]);
  int j = 0;
  for (; j + 8 <= c; j += 8) {
    int4 da = *(const int4*)(csr + start + j);
    int4 db = *(const int4*)(csr + start + j + 4);
    h2 p0 = __builtin_bit_cast(h2, Mcat[(size_t)da.x * 64 + lane]);
    h2 p1 = __builtin_bit_cast(h2, Mcat[(size_t)da.y * 64 + lane]);
    h2 p2 = __builtin_bit_cast(h2, Mcat[(size_t)da.z * 64 + lane]);
    h2 p3 = __builtin_bit_cast(h2, Mcat[(size_t)da.w * 64 + lane]);
    h2 p4 = __builtin_bit_cast(h2, Mcat[(size_t)db.x * 64 + lane]);
    h2 p5 = __builtin_bit_cast(h2, Mcat[(size_t)db.y * 64 + lane]);
    h2 p6 = __builtin_bit_cast(h2, Mcat[(size_t)db.z * 64 + lane]);
    h2 p7 = __builtin_bit_cast(h2, Mcat[(size_t)db.w * 64 + lane]);
    Sm += (float)p0.x + (float)p1.x + (float)p2.x + (float)p3.x;
    Sv += (float)p0.y + (float)p1.y + (float)p2.y + (float)p3.y;
    Sm += (float)p4.x + (float)p5.x + (float)p6.x + (float)p7.x;
    Sv += (float)p4.y + (float)p5.y + (float)p6.y + (float)p7.y;
  }
  if (j + 4 <= c) {
    int4 d4 = *(const int4*)(csr + start + j);
    h2 p0 = __builtin_bit_cast(h2, Mcat[(size_t)d4.x * 64 + lane]);
    h2 p1 = __builtin_bit_cast(h2, Mcat[(size_t)d4.y * 64 + lane]);
    h2 p2 = __builtin_bit_cast(h2, Mcat[(size_t)d4.z * 64 + lane]);
    h2 p3 = __builtin_bit_cast(h2, Mcat[(size_t)d4.w * 64 + lane]);
    Sm += (float)p0.x + (float)p1.x + (float)p2.x + (float)p3.x;
    Sv += (float)p0.y + (float)p1.y + (float)p2.y + (float)p3.y;
    j += 4;
  }
  for (; j < c; j++) {
    int d = csr[start + j];
    h2 p = __builtin_bit_cast(h2, Mcat[(size_t)d * 64 + lane]);
    Sm += (float)p.x;
    Sv += (float)p.y;
  }
  float mean = wr.x * Sm;
  float var = wr.y * Sv;
  float o = mean + sample[(size_t)r * 64 + lane] * sqrtf(var);
  float mx = o;
#pragma unroll
  for (int off = 32; off; off >>= 1) mx = fmaxf(mx, __shfl_xor(mx, off, 64));
  float ex = __expf(o - mx);
  float s = ex;
#pragma unroll
  for (int off = 32; off; off >>= 1) s += __shfl_xor(s, off, 64);
  out[(size_t)r * 64 + lane] = o - mx - logf(s);
}

// ---------------- launch ----------------
extern "C" void kernel_launch(void* const* d_in, const int* in_sizes, int n_in,
                              void* d_out, int out_size, void* d_ws, size_t ws_size,
                              hipStream_t stream) {
  (void)n_in; (void)out_size; (void)ws_size;
  const float* x    = (const float*)d_in[0];
  const float* Wm0  = (const float*)d_in[1];
  const float* bm0  = (const float*)d_in[2];
  const float* Wv0  = (const float*)d_in[3];
  const float* bv0  = (const float*)d_in[4];
  const float* Wm1  = (const float*)d_in[5];
  const float* bm1  = (const float*)d_in[6];
  const float* Wv1  = (const float*)d_in[7];
  const float* bv1  = (const float*)d_in[8];
  const float* sample = (const float*)d_in[9];
  const int* esrc   = (const int*)d_in[10];
  const int* edst   = (const int*)d_in[11];
  float* out = (float*)d_out;

  const int N = in_sizes[0] / 512;
  const int E = in_sizes[10];
  const int NB = (N + 127) >> BSHIFT;          // 128-node buckets
  const int chunk = (E + NCHUNK - 1) / NCHUNK;

  uint8_t* p = (uint8_t*)d_ws;
  size_t off = 0;
  auto alloc = [&](size_t bytes) -> void* {
    void* r = p + off;
    off += (bytes + 255) & ~(size_t)255;
    return r;
  };
  _Float16* W1t  = (_Float16*)alloc((size_t)512 * 512 * 2);
  _Float16* W2t  = (_Float16*)alloc((size_t)128 * 512 * 2);
  _Float16* Hcat = (_Float16*)alloc((size_t)N * 512 * 2);
  uint32*   Mcat = (uint32*)alloc((size_t)N * 64 * 4);
  int*   cnt    = (int*)alloc((size_t)N * 4);
  float2* dd    = (float2*)alloc((size_t)N * 8);
  int*   rs     = (int*)alloc((size_t)N * 4);
  int*   h      = (int*)alloc((size_t)NCHUNK * NB * 4);
  int*   tot    = (int*)alloc((size_t)(NB + 1) * 4);
  int*   base   = (int*)alloc((size_t)(NB + 1) * 4);
  int*   bsum   = (int*)alloc(2048);
  int*   boff   = (int*)alloc(2048);
  int*   csr    = (int*)alloc((size_t)(E + 4 * N) * 4);  // padded rows
  // bucket-sorted packed pairs only live before gemm1 writes Hcat:
  uint32* pairs = (uint32*)Hcat;   // E*4 = 12.8MB <= Hcat's 102.4MB

  const int nbN = (N + 255) / 256;

  prep_w_k<<<(512 * 512 + 255) / 256, 256, 0, stream>>>(Wm0, Wv0, Wm1, Wv1, W1t, W2t);
  hist_k<<<NCHUNK, 256, 0, stream>>>(esrc, E, chunk, h, NB);
  btotal_k<<<NB, 256, 0, stream>>>(h, tot, NB);
  bscan_k<<<1, 1024, 0, stream>>>(tot, base, NB);
  boff_k<<<NB, 256, 0, stream>>>(h, base, NB);
  bscatter_k<<<NCHUNK, 256, 0, stream>>>(esrc, edst, E, chunk, h, pairs, NB);
  countN_k<<<NB, 256, 0, stream>>>(pairs, base, cnt, dd, N);
  scan1_k<<<nbN, 256, 0, stream>>>(cnt, rs, bsum, N);
  scan2_k<<<1, 512, 0, stream>>>(bsum, boff, nbN);
  scan3_k<<<nbN, 256, 0, stream>>>(rs, boff, N);
  partC_k<<<NB, 256, 0, stream>>>(pairs, base, rs, csr, N);

  const int mt64 = (N + 63) / 64;
  const int sg64 = (mt64 + 7) / 8;
  gemm1s_k<<<sg64 * 32, 256, 0, stream>>>(x, W1t, bm0, bv0, Hcat, N, mt64);
  const int mtiles = (N + 127) / 128;
  gemm2_k<<<mtiles, 256, 0, stream>>>(Hcat, W2t, bm1, bv1, dd, Mcat, N);
  spmm_final_k<<<(N + 3) / 4, 256, 0, stream>>>(Mcat, dd, rs, cnt, csr, sample, out, N);
}